// Round 14
// baseline (203.258 us; speedup 1.0000x reference)
//
#include <hip/hip_runtime.h>
#include <hip/hip_fp16.h>
#include <math.h>

#define LEAKY 0.2f
#define HDIM 64
#define EPB 2048            // edges per fused block / histG row
#define TPB1 256
#define PERT (EPB / TPB1)   // 8 edges per thread
#define RANGE 1024          // nodes per bucket
#define RSH 10
#define KMAX 128
#define NSLICE 12
#define FIXS 2097152.0f     // 2^21 fixed-point scale (R14: was 2^22; headroom for bias pack)
#define INVFIXS (1.0f / 2097152.0f)
#define QBIAS (1u << 25)    // bias so packed u64 words accumulate carry-free (cnt<=81 safe)

// record: bits [0,11) lid, [11,27) f16 mx, [27,43) f16 my, [43,59) f16 mz

// tanh(v) = 1 - 2/(exp2(v*2*log2e)+1); exact saturation, ~1e-6 rel err (R10/11-verified)
__device__ __forceinline__ float fast_tanh(float v) {
    float e = __builtin_amdgcn_exp2f(v * 2.88539008178f);
    return 1.0f - 2.0f * __builtin_amdgcn_rcpf(e + 1.0f);
}

__device__ __forceinline__ float edge_eo(float rad, float C, bool slow,
                                         const float* sW1, const float* sb1,
                                         const float* sW2) {
    if (!slow) return fast_tanh(C * rad);  // bp1==0, rad>=0: MLP collapses to linear
    float a = 0.f;
    #pragma unroll
    for (int k = 0; k < HDIM; k++) {
        float h = fmaf(rad, sW1[k], sb1[k]);
        h = (h > 0.f) ? h : LEAKY * h;
        a = fmaf(sW2[k], h, a);
    }
    return fast_tanh(a);
}

__global__ void repack_kernel(const float* __restrict__ x, float4* __restrict__ x4, int N) {
    int i = blockIdx.x * blockDim.x + threadIdx.x;
    if (i < N) x4[i] = make_float4(x[3*i], x[3*i+1], x[3*i+2], 0.f);
}

// half-packed coords (R11-verified) + precompute folded into block 0 (R13-verified)
__global__ void repack_h_kernel(const float* __restrict__ x, uint2* __restrict__ xh, int N,
                                const float* __restrict__ Wp1, const float* __restrict__ bp1,
                                const float* __restrict__ Wp2, float* __restrict__ consts) {
    int i = blockIdx.x * blockDim.x + threadIdx.x;
    if (i < N) {
        unsigned hx = __half_as_ushort(__float2half(x[3*i]));
        unsigned hy = __half_as_ushort(__float2half(x[3*i+1]));
        unsigned hz = __half_as_ushort(__float2half(x[3*i+2]));
        xh[i] = make_uint2((hy << 16) | hx, hz);
    }
    if (blockIdx.x == 0 && threadIdx.x < 64) {
        int k = threadIdx.x;   // one wave: shuffle reduction valid
        float w1 = Wp1[k];
        float slope = (w1 >= 0.f) ? 1.f : LEAKY;
        float c = Wp2[k] * w1 * slope;
        float bnz = (bp1[k] != 0.f) ? 1.f : 0.f;
        #pragma unroll
        for (int off = 32; off > 0; off >>= 1) {
            c += __shfl_down(c, off, 64);
            bnz += __shfl_down(bnz, off, 64);
        }
        if (k == 0) { consts[0] = c; consts[1] = bnz; }
    }
}

__device__ __forceinline__ unsigned long long pack_rec(float dx, float dy, float dz,
                                                       float eo, unsigned lid) {
    unsigned hx = __half_as_ushort(__float2half(dx * eo));
    unsigned hy = __half_as_ushort(__float2half(dy * eo));
    unsigned hz = __half_as_ushort(__float2half(dz * eo));
    return (unsigned long long)lid
         | ((unsigned long long)hx << 11)
         | ((unsigned long long)hy << 27)
         | ((unsigned long long)hz << 43);
}

__device__ __forceinline__ uint2 make_record(uint2 ga, uint2 gb, int r,
                                             float C, bool slow,
                                             const float* sW1, const float* sb1,
                                             const float* sW2) {
    float ax = __half2float(__ushort_as_half((unsigned short)(ga.x & 0xFFFF)));
    float ay = __half2float(__ushort_as_half((unsigned short)(ga.x >> 16)));
    float az = __half2float(__ushort_as_half((unsigned short)(ga.y & 0xFFFF)));
    float bx = __half2float(__ushort_as_half((unsigned short)(gb.x & 0xFFFF)));
    float by = __half2float(__ushort_as_half((unsigned short)(gb.x >> 16)));
    float bz = __half2float(__ushort_as_half((unsigned short)(gb.y & 0xFFFF)));
    float dx = ax - bx, dy = ay - by, dz = az - bz;
    float rad = sqrtf(dx*dx + dy*dy + dz*dz);
    float eo = edge_eo(rad, C, slow, sW1, sb1, sW2);
    unsigned long long u = pack_rec(dx, dy, dz, eo, (unsigned)r & (RANGE - 1));
    return make_uint2((unsigned)u, (unsigned)(u >> 32));
}

// ---- count pass (R14): one WAVE per 2048-edge histG row; private replica; barrier-free
__global__ __launch_bounds__(TPB1) void count2_kernel(const int* __restrict__ ei,
                                                      unsigned* __restrict__ histG,
                                                      int E, int K, int nblk) {
    __shared__ unsigned hist[4][KMAX];
    const int w = threadIdx.x >> 6;
    const int lane = threadIdx.x & 63;
    for (int k = lane; k < KMAX; k += 64) hist[w][k] = 0;   // own replica only; no barrier
    const int sub = blockIdx.x * 4 + w;                     // fused-row id
    if (sub >= nblk) return;
    const size_t sbase = (size_t)sub * EPB;
    if (sbase + EPB <= (size_t)E) {
        const int4* p = (const int4*)(ei + sbase);
        #pragma unroll
        for (int i = 0; i < EPB / 4 / 64; i++) {            // 8 int4 per lane
            int4 v = p[lane + i * 64];
            atomicAdd(&hist[w][((unsigned)v.x) >> RSH], 1u);
            atomicAdd(&hist[w][((unsigned)v.y) >> RSH], 1u);
            atomicAdd(&hist[w][((unsigned)v.z) >> RSH], 1u);
            atomicAdd(&hist[w][((unsigned)v.w) >> RSH], 1u);
        }
    } else {
        for (size_t e = sbase + lane; e < (size_t)E; e += 64)
            atomicAdd(&hist[w][((unsigned)ei[e]) >> RSH], 1u);
    }
    for (int k = lane; k < K; k += 64)
        histG[(size_t)sub * K + k] = hist[w][k];
}

// one block per bucket b: exclusive prefix over blocks of histG[.][b] (in place) + totals[b]
__global__ __launch_bounds__(256) void colscan_kernel(unsigned* __restrict__ histG,
                                                      unsigned* __restrict__ totals,
                                                      int nblk, int K) {
    __shared__ unsigned pa[256], pb[256];
    const int b = blockIdx.x;
    const int t = threadIdx.x;
    const int chunk = (nblk + 255) / 256;
    const int r0 = t * chunk;
    unsigned s = 0;
    for (int i = 0; i < chunk; i++) {
        int r = r0 + i;
        if (r < nblk) s += histG[(size_t)r * K + b];
    }
    pa[t] = s;
    __syncthreads();
    unsigned* src = pa; unsigned* dst = pb;
    for (int off = 1; off < 256; off <<= 1) {
        unsigned v = src[t];
        if (t >= off) v += src[t - off];
        dst[t] = v;
        __syncthreads();
        unsigned* tmp = src; src = dst; dst = tmp;
    }
    unsigned excl = (t > 0) ? src[t - 1] : 0u;
    if (t == 255) totals[b] = src[255];
    unsigned run = excl;
    for (int i = 0; i < chunk; i++) {
        int r = r0 + i;
        if (r < nblk) {
            size_t a = (size_t)r * K + b;
            unsigned v = histG[a];
            histG[a] = run;
            run += v;
        }
    }
}

// ---- FUSED compute+sort (R13-verified, unchanged)
__global__ __launch_bounds__(TPB1) void fused_kernel(
        const uint2* __restrict__ xh,
        const int* __restrict__ ei,
        const float* __restrict__ Wp1, const float* __restrict__ bp1,
        const float* __restrict__ Wp2, const float* __restrict__ consts,
        const unsigned* __restrict__ histG, const unsigned* __restrict__ totals,
        uint2* __restrict__ recs, int E, int K) {
    __shared__ uint2 stage[EPB];                 // 16 KB
    __shared__ unsigned char bucket_of[EPB];     // 2 KB
    __shared__ unsigned hist[KMAX];
    __shared__ unsigned scanv[KMAX + 1];
    __shared__ unsigned gstart[KMAX];
    __shared__ unsigned sbase[KMAX + 1];
    __shared__ float sW1[HDIM], sb1[HDIM], sW2[HDIM];
    const float C = consts[0];
    const bool slow = (consts[1] != 0.f);
    if (slow) {
        for (int k = threadIdx.x; k < HDIM; k += TPB1) {
            sW1[k] = Wp1[k]; sb1[k] = bp1[k]; sW2[k] = Wp2[k];
        }
    }
    for (int k = threadIdx.x; k < K; k += TPB1) hist[k] = 0;
    if (threadIdx.x < (unsigned)K) sbase[threadIdx.x] = totals[threadIdx.x];
    __syncthreads();

    const size_t base = (size_t)blockIdx.x * EPB;
    const unsigned t = threadIdx.x;
    uint2 rc[PERT];
    unsigned bk[PERT];
    if (base + EPB <= (size_t)E && (E & 3) == 0) {
        const int4* pr = (const int4*)(ei + base);
        const int4* pc = (const int4*)(ei + (size_t)E + base);
        int4 rv0 = pr[t];
        int4 rv1 = pr[t + TPB1];
        int4 cv0 = pc[t];
        int4 cv1 = pc[t + TPB1];
        uint2 ga0 = xh[rv0.x], ga1 = xh[rv0.y], ga2 = xh[rv0.z], ga3 = xh[rv0.w];
        uint2 ga4 = xh[rv1.x], ga5 = xh[rv1.y], ga6 = xh[rv1.z], ga7 = xh[rv1.w];
        uint2 gb0 = xh[cv0.x], gb1 = xh[cv0.y], gb2 = xh[cv0.z], gb3 = xh[cv0.w];
        uint2 gb4 = xh[cv1.x], gb5 = xh[cv1.y], gb6 = xh[cv1.z], gb7 = xh[cv1.w];
        rc[0] = make_record(ga0, gb0, rv0.x, C, slow, sW1, sb1, sW2);
        rc[1] = make_record(ga1, gb1, rv0.y, C, slow, sW1, sb1, sW2);
        rc[2] = make_record(ga2, gb2, rv0.z, C, slow, sW1, sb1, sW2);
        rc[3] = make_record(ga3, gb3, rv0.w, C, slow, sW1, sb1, sW2);
        rc[4] = make_record(ga4, gb4, rv1.x, C, slow, sW1, sb1, sW2);
        rc[5] = make_record(ga5, gb5, rv1.y, C, slow, sW1, sb1, sW2);
        rc[6] = make_record(ga6, gb6, rv1.z, C, slow, sW1, sb1, sW2);
        rc[7] = make_record(ga7, gb7, rv1.w, C, slow, sW1, sb1, sW2);
        bk[0] = (unsigned)rv0.x >> RSH; bk[1] = (unsigned)rv0.y >> RSH;
        bk[2] = (unsigned)rv0.z >> RSH; bk[3] = (unsigned)rv0.w >> RSH;
        bk[4] = (unsigned)rv1.x >> RSH; bk[5] = (unsigned)rv1.y >> RSH;
        bk[6] = (unsigned)rv1.z >> RSH; bk[7] = (unsigned)rv1.w >> RSH;
        #pragma unroll
        for (int i = 0; i < PERT; i++) atomicAdd(&hist[bk[i]], 1u);
    } else {
        #pragma unroll
        for (int i = 0; i < PERT; i++) {
            size_t e = base + (size_t)i * TPB1 + t;
            bk[i] = 0xFFFFFFFFu;
            if (e < (size_t)E) {
                int r = ei[e];
                int c = ei[(size_t)E + e];
                uint2 ga = xh[r], gb = xh[c];
                rc[i] = make_record(ga, gb, r, C, slow, sW1, sb1, sW2);
                bk[i] = (unsigned)r >> RSH;
                atomicAdd(&hist[bk[i]], 1u);
            }
        }
    }
    __syncthreads();
    if (t == 0) {
        unsigned a = 0;
        for (int k = 0; k < K; k++) { scanv[k] = a; a += hist[k]; }
        scanv[K] = a;
    } else if (t == 64) {  // separate wave: overlap the two serial scans
        unsigned a = 0;
        for (int k = 0; k < K; k++) { unsigned v = sbase[k]; sbase[k] = a; a += v; }
        sbase[K] = a;
    }
    __syncthreads();
    if (t < (unsigned)K)
        gstart[t] = sbase[t] + histG[(size_t)blockIdx.x * K + t];
    for (int k = t; k < K; k += TPB1) hist[k] = scanv[k];  // running cursors
    __syncthreads();
    #pragma unroll
    for (int i = 0; i < PERT; i++) {
        if (bk[i] != 0xFFFFFFFFu) {
            unsigned slot = atomicAdd(&hist[bk[i]], 1u);
            stage[slot] = rc[i];
            bucket_of[slot] = (unsigned char)bk[i];
        }
    }
    __syncthreads();
    unsigned total = scanv[K];
    for (unsigned j = t; j < total; j += TPB1) {
        unsigned b_ = bucket_of[j];
        recs[(size_t)gstart[b_] + (j - scanv[b_])] = stage[j];
    }
}

// ---- fallback pieces (R7/R12-verified) ----
__global__ __launch_bounds__(TPB1) void count_kernel(const int* __restrict__ ei,
                                                     unsigned* __restrict__ cnts,
                                                     int E, int K) {
    __shared__ unsigned hist[4][KMAX];
    int w = threadIdx.x >> 6;
    for (int k = threadIdx.x; k < 4 * KMAX; k += TPB1) ((unsigned*)hist)[k] = 0;
    __syncthreads();
    int base = blockIdx.x * EPB;
    #pragma unroll
    for (int i = 0; i < PERT; i++) {
        int e = base + i * TPB1 + threadIdx.x;
        if (e < E) atomicAdd(&hist[w][((unsigned)ei[e]) >> RSH], 1u);
    }
    __syncthreads();
    for (int k = threadIdx.x; k < K; k += TPB1) {
        unsigned t = hist[0][k] + hist[1][k] + hist[2][k] + hist[3][k];
        if (t) atomicAdd(&cnts[k], t);
    }
}

__global__ void scan_kernel(const unsigned* __restrict__ cnts,
                            unsigned* __restrict__ base,
                            unsigned* __restrict__ cursor, int K) {
    if (threadIdx.x == 0) {
        unsigned acc = 0;
        for (int k = 0; k < K; k++) { base[k] = acc; cursor[k] = acc; acc += cnts[k]; }
        base[K] = acc;
    }
}

__global__ void precompute_kernel(const float* __restrict__ Wp1,
                                  const float* __restrict__ bp1,
                                  const float* __restrict__ Wp2,
                                  float* __restrict__ consts) {
    int k = threadIdx.x;
    float w1 = Wp1[k];
    float slope = (w1 >= 0.f) ? 1.f : LEAKY;
    float c = Wp2[k] * w1 * slope;
    float bnz = (bp1[k] != 0.f) ? 1.f : 0.f;
    #pragma unroll
    for (int off = 32; off > 0; off >>= 1) {
        c += __shfl_down(c, off, 64);
        bnz += __shfl_down(bnz, off, 64);
    }
    if (k == 0) { consts[0] = c; consts[1] = bnz; }
}

__global__ __launch_bounds__(TPB1) void bin_kernel(
        const float* __restrict__ x, const float4* __restrict__ x4, int use4,
        const int* __restrict__ ei,
        const float* __restrict__ Wp1, const float* __restrict__ bp1,
        const float* __restrict__ Wp2, const float* __restrict__ consts,
        unsigned* __restrict__ cursor, uint2* __restrict__ recs, int E, int K) {
    __shared__ uint2 stage[EPB];
    __shared__ unsigned char bucket_of[EPB];
    __shared__ unsigned hist[KMAX];
    __shared__ unsigned scanv[KMAX + 1];
    __shared__ unsigned gstart[KMAX];
    __shared__ float sW1[HDIM], sb1[HDIM], sW2[HDIM];
    const float C = consts[0];
    const bool slow = (consts[1] != 0.f);
    if (slow) {
        for (int k = threadIdx.x; k < HDIM; k += TPB1) {
            sW1[k] = Wp1[k]; sb1[k] = bp1[k]; sW2[k] = Wp2[k];
        }
    }
    for (int k = threadIdx.x; k < K; k += TPB1) hist[k] = 0;
    __syncthreads();

    int base = blockIdx.x * EPB;
    uint2 rc[PERT];
    unsigned bk[PERT];
    #pragma unroll
    for (int i = 0; i < PERT; i++) {
        int e = base + i * TPB1 + threadIdx.x;
        bk[i] = 0xFFFFFFFFu;
        if (e < E) {
            int r = ei[e];
            int c = ei[(size_t)E + e];
            float dx, dy, dz;
            if (use4) {
                float4 a = x4[r], b = x4[c];
                dx = a.x - b.x; dy = a.y - b.y; dz = a.z - b.z;
            } else {
                dx = x[3*r]   - x[3*c];
                dy = x[3*r+1] - x[3*c+1];
                dz = x[3*r+2] - x[3*c+2];
            }
            float rad = sqrtf(dx*dx + dy*dy + dz*dz);
            float eo = edge_eo(rad, C, slow, sW1, sb1, sW2);
            unsigned long long u = pack_rec(dx, dy, dz, eo, (unsigned)r & (RANGE - 1));
            rc[i] = make_uint2((unsigned)u, (unsigned)(u >> 32));
            bk[i] = (unsigned)r >> RSH;
            atomicAdd(&hist[bk[i]], 1u);
        }
    }
    __syncthreads();
    if (threadIdx.x == 0) {
        unsigned a = 0;
        for (int k = 0; k < K; k++) { scanv[k] = a; a += hist[k]; }
        scanv[K] = a;
    }
    __syncthreads();
    if (threadIdx.x < (unsigned)K) {
        unsigned c_ = scanv[threadIdx.x + 1] - scanv[threadIdx.x];
        gstart[threadIdx.x] = c_ ? atomicAdd(&cursor[threadIdx.x], c_) : 0u;
    }
    for (int k = threadIdx.x; k < K; k += TPB1) hist[k] = scanv[k];
    __syncthreads();
    #pragma unroll
    for (int i = 0; i < PERT; i++) {
        if (bk[i] != 0xFFFFFFFFu) {
            unsigned slot = atomicAdd(&hist[bk[i]], 1u);
            stage[slot] = rc[i];
            bucket_of[slot] = (unsigned char)bk[i];
        }
    }
    __syncthreads();
    unsigned total = scanv[K];
    for (unsigned j = threadIdx.x; j < total; j += TPB1) {
        unsigned b_ = bucket_of[j];
        recs[(size_t)gstart[b_] + (j - scanv[b_])] = stage[j];
    }
}

// R14: 2 biased-pack u64 LDS atomics per record (was 4 u32)
__device__ __forceinline__ void proc_rec2(uint2 r, unsigned long long (*acc)[RANGE]) {
    unsigned long long u = ((unsigned long long)r.y << 32) | r.x;
    unsigned lid = (unsigned)(u & (RANGE - 1));
    float mx = __half2float(__ushort_as_half((unsigned short)((u >> 11) & 0xFFFF)));
    float my = __half2float(__ushort_as_half((unsigned short)((u >> 27) & 0xFFFF)));
    float mz = __half2float(__ushort_as_half((unsigned short)((u >> 43) & 0xFFFF)));
    unsigned qx = (unsigned)(__float2int_rn(mx * FIXS)) + QBIAS;
    unsigned qy = (unsigned)(__float2int_rn(my * FIXS)) + QBIAS;
    unsigned qz = (unsigned)(__float2int_rn(mz * FIXS)) + QBIAS;
    atomicAdd(&acc[0][lid], (unsigned long long)qx | ((unsigned long long)qy << 32));
    atomicAdd(&acc[1][lid], (unsigned long long)qz | (1ULL << 32));
}

// totals-based reduce (R13 structure), u64-packed accumulators, 4x unroll
__global__ __launch_bounds__(256) void reduce_kernel(
        const uint2* __restrict__ recs, const unsigned* __restrict__ totals,
        float4* __restrict__ slices, int N, int K) {
    __shared__ unsigned long long acc[2][RANGE];   // 16 KB
    __shared__ unsigned sbase[KMAX + 1];
    int b = blockIdx.x / NSLICE;
    int s = blockIdx.x % NSLICE;
    if (threadIdx.x < (unsigned)K) sbase[threadIdx.x] = totals[threadIdx.x];
    for (int i = threadIdx.x; i < RANGE; i += 256) { acc[0][i] = 0ULL; acc[1][i] = 0ULL; }
    __syncthreads();
    if (threadIdx.x == 0) {
        unsigned a = 0;
        for (int k = 0; k < K; k++) { unsigned v = sbase[k]; sbase[k] = a; a += v; }
        sbase[K] = a;
    }
    __syncthreads();
    unsigned lo = sbase[b], hi = sbase[b + 1];
    unsigned cnt = hi - lo;
    unsigned per = (cnt + NSLICE - 1) / NSLICE;
    unsigned st = lo + (unsigned)s * per;
    unsigned en = st + per; if (en > hi) en = hi;
    unsigned j = st + threadIdx.x;
    if (st < hi) {
        while (j + 768 < en) {          // 4 loads in flight
            uint2 r0 = recs[j];
            uint2 r1 = recs[j + 256];
            uint2 r2 = recs[j + 512];
            uint2 r3 = recs[j + 768];
            proc_rec2(r0, acc); proc_rec2(r1, acc);
            proc_rec2(r2, acc); proc_rec2(r3, acc);
            j += 1024;
        }
        while (j < en) { proc_rec2(recs[j], acc); j += 256; }
    }
    __syncthreads();
    int nbase = b * RANGE;
    for (int i = threadIdx.x; i < RANGE; i += 256) {
        int node = nbase + i;
        if (node < N) {
            unsigned long long a0 = acc[0][i], a1 = acc[1][i];
            unsigned c_ = (unsigned)(a1 >> 32);
            unsigned cb = c_ * QBIAS;
            slices[(size_t)s * N + node] = make_float4(
                (float)(int)((unsigned)a0 - cb)         * INVFIXS,
                (float)(int)((unsigned)(a0 >> 32) - cb) * INVFIXS,
                (float)(int)((unsigned)a1 - cb)         * INVFIXS,
                (float)c_);
        }
    }
}

__global__ void node_kernel(const float* __restrict__ x, const float* __restrict__ vel_norm,
                            const float* __restrict__ vel,
                            const float* __restrict__ W1, const float* __restrict__ b1,
                            const float* __restrict__ W2, const float* __restrict__ b2,
                            const float4* __restrict__ slices,
                            float* __restrict__ out, int N, int S) {
    __shared__ float sW1[HDIM], sb1[HDIM], sW2[HDIM];
    for (int k = threadIdx.x; k < HDIM; k += blockDim.x) {
        sW1[k] = W1[k]; sb1[k] = b1[k]; sW2[k] = W2[k];
    }
    __syncthreads();
    int i = blockIdx.x * blockDim.x + threadIdx.x;
    if (i >= N) return;
    float sx = 0.f, sy = 0.f, sz = 0.f, sc = 0.f;
    for (int s = 0; s < S; s++) {
        float4 v = slices[(size_t)s * N + i];
        sx += v.x; sy += v.y; sz += v.z; sc += v.w;
    }
    float vn = vel_norm[i];
    float a = b2[0];
    #pragma unroll
    for (int k = 0; k < HDIM; k++) {
        float h = fmaf(vn, sW1[k], sb1[k]);
        h = (h > 0.f) ? h : LEAKY * h;
        a = fmaf(sW2[k], h, a);
    }
    float inv = 1.0f / fmaxf(sc, 1.0f);
    out[3*i]     = x[3*i]     + sx * inv + vel[3*i]     * a;
    out[3*i + 1] = x[3*i + 1] + sy * inv + vel[3*i + 1] * a;
    out[3*i + 2] = x[3*i + 2] + sz * inv + vel[3*i + 2] * a;
}

// fallback reduce (basep form, u32 4-atomic — R12-verified path)
__device__ __forceinline__ void proc_rec(uint2 r, unsigned (*acc)[RANGE]) {
    unsigned long long u = ((unsigned long long)r.y << 32) | r.x;
    unsigned lid = (unsigned)(u & (RANGE - 1));
    float mx = __half2float(__ushort_as_half((unsigned short)((u >> 11) & 0xFFFF)));
    float my = __half2float(__ushort_as_half((unsigned short)((u >> 27) & 0xFFFF)));
    float mz = __half2float(__ushort_as_half((unsigned short)((u >> 43) & 0xFFFF)));
    atomicAdd(&acc[0][lid], (unsigned)(int)__float2int_rn(mx * FIXS));
    atomicAdd(&acc[1][lid], (unsigned)(int)__float2int_rn(my * FIXS));
    atomicAdd(&acc[2][lid], (unsigned)(int)__float2int_rn(mz * FIXS));
    atomicAdd(&acc[3][lid], 1u);
}

__global__ __launch_bounds__(256) void reduce_basep_kernel(
        const uint2* __restrict__ recs, const unsigned* __restrict__ base,
        float4* __restrict__ slices, int N, int K) {
    __shared__ unsigned acc[4][RANGE];
    int b = blockIdx.x / NSLICE;
    int s = blockIdx.x % NSLICE;
    for (int i = threadIdx.x; i < RANGE; i += 256) {
        acc[0][i] = 0u; acc[1][i] = 0u; acc[2][i] = 0u; acc[3][i] = 0u;
    }
    __syncthreads();
    unsigned lo = base[b], hi = base[b + 1];
    unsigned cnt = hi - lo;
    unsigned per = (cnt + NSLICE - 1) / NSLICE;
    unsigned st = lo + (unsigned)s * per;
    unsigned en = st + per; if (en > hi) en = hi;
    unsigned j = st + threadIdx.x;
    if (st < hi) {
        while (j + 256 < en) {
            uint2 r0 = recs[j];
            uint2 r1 = recs[j + 256];
            proc_rec(r0, acc);
            proc_rec(r1, acc);
            j += 512;
        }
        while (j < en) { proc_rec(recs[j], acc); j += 256; }
    }
    __syncthreads();
    int nbase = b * RANGE;
    for (int i = threadIdx.x; i < RANGE; i += 256) {
        int node = nbase + i;
        if (node < N)
            slices[(size_t)s * N + node] =
                make_float4((float)(int)acc[0][i] * INVFIXS,
                            (float)(int)acc[1][i] * INVFIXS,
                            (float)(int)acc[2][i] * INVFIXS,
                            (float)acc[3][i]);
    }
}

// final fallback: plain device-scope atomics
__global__ void edge_atomic_kernel(const float* __restrict__ x, const int* __restrict__ ei,
                                   const float* __restrict__ Wp1, const float* __restrict__ bp1,
                                   const float* __restrict__ Wp2, const float* __restrict__ consts,
                                   float* __restrict__ acc, int E) {
    __shared__ float sW1[HDIM], sb1[HDIM], sW2[HDIM];
    const float C = consts[0];
    const bool slow = (consts[1] != 0.f);
    if (slow) {
        for (int k = threadIdx.x; k < HDIM; k += blockDim.x) {
            sW1[k] = Wp1[k]; sb1[k] = bp1[k]; sW2[k] = Wp2[k];
        }
        __syncthreads();
    }
    int e = blockIdx.x * blockDim.x + threadIdx.x;
    if (e >= E) return;
    int r = ei[e];
    int c = ei[E + e];
    float dx = x[3*r] - x[3*c];
    float dy = x[3*r+1] - x[3*c+1];
    float dz = x[3*r+2] - x[3*c+2];
    float rad = sqrtf(dx*dx + dy*dy + dz*dz);
    float eo = edge_eo(rad, C, slow, sW1, sb1, sW2);
    float* basep = acc + ((size_t)r << 2);
    atomicAdd(basep + 0, dx * eo);
    atomicAdd(basep + 1, dy * eo);
    atomicAdd(basep + 2, dz * eo);
    atomicAdd(basep + 3, 1.f);
}

extern "C" void kernel_launch(void* const* d_in, const int* in_sizes, int n_in,
                              void* d_out, int out_size, void* d_ws, size_t ws_size,
                              hipStream_t stream) {
    const float* x        = (const float*)d_in[0];
    const float* vel_norm = (const float*)d_in[1];
    const float* vel      = (const float*)d_in[2];
    const int*   ei       = (const int*)  d_in[3];
    const float* W1       = (const float*)d_in[4];
    const float* b1       = (const float*)d_in[5];
    const float* W2       = (const float*)d_in[6];
    const float* b2       = (const float*)d_in[7];
    const float* Wp1      = (const float*)d_in[8];
    const float* bp1      = (const float*)d_in[9];
    const float* Wp2      = (const float*)d_in[10];

    const int N = in_sizes[0] / 3;
    const int E = in_sizes[3] / 2;
    const int K = (N + RANGE - 1) / RANGE;
    const int nblk = (E + EPB - 1) / EPB;

    size_t rec_bytes   = (size_t)E * sizeof(uint2);
    size_t slice_bytes = (size_t)NSLICE * N * sizeof(float4);
    size_t x4_bytes    = (size_t)N * sizeof(float4);
    size_t histG_bytes = (size_t)nblk * K * sizeof(unsigned);

    // split layout: [recs][slices][xh][histG][totals][consts]
    size_t sp_slices = rec_bytes;
    size_t sp_xh     = sp_slices + slice_bytes;
    size_t sp_hist   = sp_xh + x4_bytes;
    size_t sp_tot    = sp_hist + histG_bytes;
    size_t sp_const  = (sp_tot + (size_t)(K + 1) * sizeof(unsigned) + 15) & ~(size_t)15;
    size_t need_split = sp_const + 32;

    // fallback layout: [slices][recs][x4][small: cnts|base|cursor|consts]
    size_t small_bytes = (size_t)(KMAX + (KMAX + 1) + KMAX) * sizeof(unsigned) + 32;
    size_t fu_recs  = slice_bytes;
    size_t fu_x4    = fu_recs + rec_bytes;
    size_t fu_small = fu_x4 + x4_bytes;
    size_t need_fused = fu_small + small_bytes;

    if (K <= KMAX && ws_size >= need_split) {
        uint2*    recs   = (uint2*)   d_ws;
        float4*   slices = (float4*)  ((char*)d_ws + sp_slices);
        uint2*    xh     = (uint2*)   ((char*)d_ws + sp_xh);
        unsigned* histG  = (unsigned*)((char*)d_ws + sp_hist);
        unsigned* totals = (unsigned*)((char*)d_ws + sp_tot);
        float*    consts = (float*)   ((char*)d_ws + sp_const);

        repack_h_kernel<<<(N + 255) / 256, 256, 0, stream>>>(x, xh, N, Wp1, bp1, Wp2, consts);
        count2_kernel<<<(nblk + 3) / 4, TPB1, 0, stream>>>(ei, histG, E, K, nblk);
        colscan_kernel<<<K, 256, 0, stream>>>(histG, totals, nblk, K);
        fused_kernel<<<nblk, TPB1, 0, stream>>>(xh, ei, Wp1, bp1, Wp2, consts,
                                                histG, totals, recs, E, K);
        reduce_kernel<<<K * NSLICE, 256, 0, stream>>>(recs, totals, slices, N, K);
        node_kernel<<<(N + 255) / 256, 256, 0, stream>>>(x, vel_norm, vel, W1, b1, W2, b2,
                                                         slices, (float*)d_out, N, NSLICE);
    } else if (K <= KMAX && ws_size >= need_fused) {
        float4*   slices = (float4*)  d_ws;
        uint2*    recs   = (uint2*)   ((char*)d_ws + fu_recs);
        float4*   x4     = (float4*)  ((char*)d_ws + fu_x4);
        unsigned* cnts   = (unsigned*)((char*)d_ws + fu_small);
        unsigned* basep  = cnts + KMAX;
        unsigned* cursor = basep + KMAX + 1;
        float*    consts = (float*)(cursor + KMAX);

        hipMemsetAsync(cnts, 0, small_bytes, stream);
        precompute_kernel<<<1, 64, 0, stream>>>(Wp1, bp1, Wp2, consts);
        repack_kernel<<<(N + 255) / 256, 256, 0, stream>>>(x, x4, N);
        count_kernel<<<nblk, TPB1, 0, stream>>>(ei, cnts, E, K);
        scan_kernel<<<1, 64, 0, stream>>>(cnts, basep, cursor, K);
        bin_kernel<<<nblk, TPB1, 0, stream>>>(x, x4, 1, ei, Wp1, bp1, Wp2, consts,
                                              cursor, recs, E, K);
        reduce_basep_kernel<<<K * NSLICE, 256, 0, stream>>>(recs, basep, slices, N, K);
        node_kernel<<<(N + 255) / 256, 256, 0, stream>>>(x, vel_norm, vel, W1, b1, W2, b2,
                                                         slices, (float*)d_out, N, NSLICE);
    } else {
        float* acc    = (float*)d_ws;
        float* consts = (float*)((char*)d_ws + (size_t)N * sizeof(float4));
        hipMemsetAsync(d_ws, 0, (size_t)N * sizeof(float4) + 32, stream);
        precompute_kernel<<<1, 64, 0, stream>>>(Wp1, bp1, Wp2, consts);
        edge_atomic_kernel<<<(E + 255) / 256, 256, 0, stream>>>(x, ei, Wp1, bp1, Wp2,
                                                                consts, acc, E);
        node_kernel<<<(N + 255) / 256, 256, 0, stream>>>(x, vel_norm, vel, W1, b1, W2, b2,
                                                         (const float4*)acc, (float*)d_out, N, 1);
    }
}